// Round 1
// baseline (920.213 us; speedup 1.0000x reference)
//
#include <hip/hip_runtime.h>
#include <hip/hip_fp16.h>

// DeltaNet chunkwise. b=4,h=4,L=4096,dk=dv=256,c=32 -> 16 heads x 128 chunks.
// Phase 1: per-chunk (2048 WGs): normalize, A=stril(kb k^T), register forward-sub
//          solve for u=(I+A)^-1 (v*beta), w=(I+A)^-1 (k*beta), att=tril(q k^T), kT.
// Phase 2: per (head, dv-block32) (128 WGs): sequential scan, S in f32 MFMA accs,
//          fp16 S copy in LDS (column-major) for the [w;q]@S B-operand.

typedef _Float16 half8 __attribute__((ext_vector_type(8)));
typedef float f32x4 __attribute__((ext_vector_type(4)));
typedef unsigned int u32x2 __attribute__((ext_vector_type(2)));
typedef unsigned int u32x4 __attribute__((ext_vector_type(4)));

__device__ __forceinline__ unsigned short f2h(float f) {
    return __half_as_ushort(__float2half(f));
}
__device__ __forceinline__ float h2f(unsigned short u) {
    return __half2float(__ushort_as_half(u));
}
__device__ __forceinline__ unsigned int pk2(float a, float b) {
    return (unsigned int)f2h(a) | ((unsigned int)f2h(b) << 16);
}

#define MFMA16(a, b, c) __builtin_amdgcn_mfma_f32_16x16x32_f16((a), (b), (c), 0, 0, 0)

// ---------------------------------------------------------------- phase 1
__global__ __launch_bounds__(256, 2) void p1_kernel(
    const float* __restrict__ qg, const float* __restrict__ kg,
    const float* __restrict__ vg, const float* __restrict__ bg,
    unsigned short* __restrict__ qn_w, unsigned short* __restrict__ w_w,
    unsigned short* __restrict__ kT_w, unsigned short* __restrict__ u_w,
    unsigned short* __restrict__ att_w)
{
    __shared__ unsigned short kn_l[32][264];   // normalized k, row-major (pad 264)
    __shared__ unsigned short kb_l[32][264];   // k*beta
    __shared__ unsigned short qn_l[32][264];   // normalized q
    __shared__ float          A_l[32][34];     // strict-lower A, zero elsewhere
    __shared__ unsigned short att_l[32][40];   // tril(q k^T) fp16
    __shared__ unsigned short wst[256][40];    // w column staging [dk][c]
    __shared__ float          beta_l[32];

    const int tid = threadIdx.x;
    const int g   = blockIdx.x;      // global chunk id
    const int bh  = g >> 7;          // head
    const int ci  = g & 127;         // chunk within head
    const size_t inBase = ((size_t)bh * 4096 + (size_t)ci * 32) * 256;

    if (tid < 32) beta_l[tid] = bg[(size_t)bh * 4096 + ci * 32 + tid];

    const int r = tid >> 3, p = tid & 7, d0 = p * 32;   // 8 threads per row
    const float bval = bg[(size_t)bh * 4096 + ci * 32 + r];

    // ---- K: normalize -> kn_l, kb_l ----
    {
        float vals[32]; float ss = 0.f;
        const float4* src = (const float4*)(kg + inBase + (size_t)r * 256 + d0);
        #pragma unroll
        for (int i = 0; i < 8; i++) {
            float4 v4 = src[i];
            vals[4*i+0] = v4.x; vals[4*i+1] = v4.y; vals[4*i+2] = v4.z; vals[4*i+3] = v4.w;
            ss += v4.x*v4.x + v4.y*v4.y + v4.z*v4.z + v4.w*v4.w;
        }
        ss += __shfl_xor(ss, 1); ss += __shfl_xor(ss, 2); ss += __shfl_xor(ss, 4);
        const float rn = rsqrtf(ss);
        unsigned int* dstn = (unsigned int*)&kn_l[r][d0];
        unsigned int* dstb = (unsigned int*)&kb_l[r][d0];
        #pragma unroll
        for (int i = 0; i < 16; i++) {
            float a = vals[2*i] * rn, b = vals[2*i+1] * rn;
            dstn[i] = pk2(a, b);
            dstb[i] = pk2(a * bval, b * bval);
        }
    }
    // ---- Q: normalize -> qn_l + global qn ----
    {
        float vals[32]; float ss = 0.f;
        const float4* src = (const float4*)(qg + inBase + (size_t)r * 256 + d0);
        #pragma unroll
        for (int i = 0; i < 8; i++) {
            float4 v4 = src[i];
            vals[4*i+0] = v4.x; vals[4*i+1] = v4.y; vals[4*i+2] = v4.z; vals[4*i+3] = v4.w;
            ss += v4.x*v4.x + v4.y*v4.y + v4.z*v4.z + v4.w*v4.w;
        }
        ss += __shfl_xor(ss, 1); ss += __shfl_xor(ss, 2); ss += __shfl_xor(ss, 4);
        const float rn = rsqrtf(ss);
        unsigned int pq[16];
        #pragma unroll
        for (int i = 0; i < 16; i++) pq[i] = pk2(vals[2*i] * rn, vals[2*i+1] * rn);
        unsigned int* dstq = (unsigned int*)&qn_l[r][d0];
        #pragma unroll
        for (int i = 0; i < 16; i++) dstq[i] = pq[i];
        u32x4* og = (u32x4*)(qn_w + ((size_t)g * 32 + r) * 256 + d0);
        #pragma unroll
        for (int m = 0; m < 4; m++) {
            u32x4 val; val.x = pq[4*m]; val.y = pq[4*m+1]; val.z = pq[4*m+2]; val.w = pq[4*m+3];
            og[m] = val;
        }
    }
    __syncthreads();

    // ---- MFMA: A = stril(kb kn^T), att = tril(qn kn^T). 4 waves x 1 tile each ----
    {
        const int wid = tid >> 6, lane = tid & 63;
        const int mt = wid >> 1, ntt = wid & 1;
        const int l15 = lane & 15, l4 = lane >> 4;
        f32x4 accA = {0.f, 0.f, 0.f, 0.f}, accT = {0.f, 0.f, 0.f, 0.f};
        #pragma unroll
        for (int kk = 0; kk < 8; kk++) {
            half8 bfr = *(const half8*)&kn_l[ntt*16 + l15][kk*32 + l4*8];
            half8 afr = *(const half8*)&kb_l[mt*16 + l15][kk*32 + l4*8];
            half8 qfr = *(const half8*)&qn_l[mt*16 + l15][kk*32 + l4*8];
            accA = MFMA16(afr, bfr, accA);
            accT = MFMA16(qfr, bfr, accT);
        }
        #pragma unroll
        for (int j = 0; j < 4; j++) {
            int row = mt*16 + l4*4 + j, col = ntt*16 + l15;
            A_l[row][col]   = (row > col)  ? accA[j] : 0.f;
            att_l[row][col] = (row >= col) ? f2h(accT[j]) : (unsigned short)0;
        }
    }
    // ---- kT copy-out (reads kn_l, independent of A_l) ----
    {
        const int dk = tid;
        unsigned short arr[32];
        #pragma unroll
        for (int j = 0; j < 32; j++) arr[j] = kn_l[j][dk];
        u32x4* dst = (u32x4*)(kT_w + ((size_t)g * 256 + dk) * 32);
        #pragma unroll
        for (int m = 0; m < 4; m++) {
            u32x4 val;
            val.x = (unsigned)arr[8*m+0] | ((unsigned)arr[8*m+1] << 16);
            val.y = (unsigned)arr[8*m+2] | ((unsigned)arr[8*m+3] << 16);
            val.z = (unsigned)arr[8*m+4] | ((unsigned)arr[8*m+5] << 16);
            val.w = (unsigned)arr[8*m+6] | ((unsigned)arr[8*m+7] << 16);
            dst[m] = val;
        }
    }
    __syncthreads();

    // ---- register forward substitution: (I+A) x = rhs, per-thread column ----
    {
        const int c = tid;   // 0..255: dv column for u, dk column for w
        float xu[32], xw[32];
        #pragma unroll
        for (int j = 0; j < 32; j++) {
            xu[j] = vg[inBase + (size_t)j * 256 + c] * beta_l[j];
            xw[j] = h2f(kb_l[j][c]);
        }
        #pragma unroll
        for (int i = 1; i < 32; i++) {
            float su = xu[i], sw = xw[i];
            const float2* Ar = (const float2*)(&A_l[i][0]);   // A[i][i]==0 pads odd i
            #pragma unroll
            for (int h = 0; h < (i + 1) / 2; h++) {
                float2 a = Ar[h];
                su -= a.x * xu[2*h] + a.y * xu[2*h+1];
                sw -= a.x * xw[2*h] + a.y * xw[2*h+1];
            }
            xu[i] = su; xw[i] = sw;
        }
        // u out, column-major [dv][chunk] fp16
        unsigned int up[16];
        #pragma unroll
        for (int j = 0; j < 16; j++) up[j] = pk2(xu[2*j], xu[2*j+1]);
        u32x4* du = (u32x4*)(u_w + ((size_t)g * 256 + c) * 32);
        #pragma unroll
        for (int m = 0; m < 4; m++) {
            u32x4 val; val.x = up[4*m]; val.y = up[4*m+1]; val.z = up[4*m+2]; val.w = up[4*m+3];
            du[m] = val;
        }
        // w staged column-major in LDS for row-major global write
        unsigned int* wd = (unsigned int*)&wst[c][0];
        #pragma unroll
        for (int j = 0; j < 16; j++) wd[j] = pk2(xw[2*j], xw[2*j+1]);
    }
    __syncthreads();

    // ---- w copy-out row-major ----
    {
        const int rr = tid >> 3, pp = tid & 7, dd0 = pp * 32;
        unsigned short arr[32];
        #pragma unroll
        for (int i = 0; i < 32; i++) arr[i] = wst[dd0 + i][rr];
        u32x4* dst = (u32x4*)(w_w + ((size_t)g * 32 + rr) * 256 + dd0);
        #pragma unroll
        for (int m = 0; m < 4; m++) {
            u32x4 val;
            val.x = (unsigned)arr[8*m+0] | ((unsigned)arr[8*m+1] << 16);
            val.y = (unsigned)arr[8*m+2] | ((unsigned)arr[8*m+3] << 16);
            val.z = (unsigned)arr[8*m+4] | ((unsigned)arr[8*m+5] << 16);
            val.w = (unsigned)arr[8*m+6] | ((unsigned)arr[8*m+7] << 16);
            dst[m] = val;
        }
    }
    // ---- att copy-out ----
    if (tid < 128) {
        const int rr = tid >> 2, j0 = (tid & 3) * 8;
        u32x4 vv = *(const u32x4*)&att_l[rr][j0];
        *(u32x4*)(att_w + (size_t)g * 1024 + rr * 32 + j0) = vv;
    }
}

// ---------------------------------------------------------------- phase 2
__global__ __launch_bounds__(256, 1) void p2_kernel(
    const unsigned short* __restrict__ qn_w, const unsigned short* __restrict__ w_w,
    const unsigned short* __restrict__ kT_w, const unsigned short* __restrict__ u_w,
    const unsigned short* __restrict__ att_w, float* __restrict__ outp)
{
    __shared__ unsigned short S_cm[32][264];   // S slab fp16, column-major [dv][dk]
    __shared__ unsigned short uadj[32][40];    // u_adj fp16, column-major [dv][chunk]

    const int tid = threadIdx.x;
    const int bid = blockIdx.x;
    const int bh  = bid & 15;        // head (same-head WGs share XCD via %8)
    const int dvb = bid >> 4;        // dv block (8 x 32)
    const int dv0 = dvb * 32;
    const int wid = tid >> 6, lane = tid & 63;
    const int mh  = wid >> 1;        // 0: w-rows / u_adj owner, 1: q-rows / o owner
    const int ntw = wid & 1;         // dv 16-col tile
    const int l15 = lane & 15, l4 = lane >> 4;

    // zero S_cm (S_0 = 0)
    for (int i = tid; i < 32 * 264 / 2; i += 256) ((unsigned int*)S_cm)[i] = 0u;

    f32x4 accS[8];
    #pragma unroll
    for (int d = 0; d < 8; d++) accS[d] = (f32x4){0.f, 0.f, 0.f, 0.f};

    const unsigned short* wqbase = mh ? qn_w : w_w;

    // prefetch t=0 A-fragments of [w;q]
    half8 wqA[8], wqB[8];
    {
        const size_t g0 = (size_t)bh * 128;
        #pragma unroll
        for (int kk = 0; kk < 8; kk++) {
            wqA[kk] = *(const half8*)(wqbase + (g0*32 +      l15) * 256 + kk*32 + l4*8);
            wqB[kk] = *(const half8*)(wqbase + (g0*32 + 16 + l15) * 256 + kk*32 + l4*8);
        }
    }
    __syncthreads();

    for (int t = 0; t < 128; ++t) {
        const size_t g = (size_t)bh * 128 + t;

        // early loads consumed after the barrier
        half8 kfrag[8];
        #pragma unroll
        for (int dt = 0; dt < 8; dt++)
            kfrag[dt] = *(const half8*)(kT_w + (g*256 + mh*128 + dt*16 + l15) * 32 + l4*8);
        half8 att0 = {}, att1 = {};
        u32x2 u0 = {}, u1 = {};
        if (mh) {
            att0 = *(const half8*)(att_w + (g*32 +      l15) * 32 + l4*8);
            att1 = *(const half8*)(att_w + (g*32 + 16 + l15) * 32 + l4*8);
        } else {
            u0 = *(const u32x2*)(u_w + (g*256 + dv0 + ntw*16 + l15) * 32 +      l4*4);
            u1 = *(const u32x2*)(u_w + (g*256 + dv0 + ntw*16 + l15) * 32 + 16 + l4*4);
        }

        // [w;q] @ S : this wave's 32 M-rows x 16 N-cols, K=256
        f32x4 acc0 = {0.f,0.f,0.f,0.f}, acc1 = {0.f,0.f,0.f,0.f};
        #pragma unroll
        for (int kk = 0; kk < 8; kk++) {
            half8 b = *(const half8*)&S_cm[ntw*16 + l15][kk*32 + l4*8];
            acc0 = MFMA16(wqA[kk], b, acc0);
            acc1 = MFMA16(wqB[kk], b, acc1);
        }
        if (!mh) {   // u_adj = u - w@S -> LDS (column-major fp16)
            u32x2 w0, w1;
            w0.x = pk2(h2f((unsigned short)(u0.x & 0xffff)) - acc0[0],
                       h2f((unsigned short)(u0.x >> 16))    - acc0[1]);
            w0.y = pk2(h2f((unsigned short)(u0.y & 0xffff)) - acc0[2],
                       h2f((unsigned short)(u0.y >> 16))    - acc0[3]);
            w1.x = pk2(h2f((unsigned short)(u1.x & 0xffff)) - acc1[0],
                       h2f((unsigned short)(u1.x >> 16))    - acc1[1]);
            w1.y = pk2(h2f((unsigned short)(u1.y & 0xffff)) - acc1[2],
                       h2f((unsigned short)(u1.y >> 16))    - acc1[3]);
            *(u32x2*)&uadj[ntw*16 + l15][l4*4]      = w0;
            *(u32x2*)&uadj[ntw*16 + l15][16 + l4*4] = w1;
        }
        __syncthreads();

        // prefetch next step's [w;q] fragments
        if (t < 127) {
            const size_t g2 = g + 1;
            #pragma unroll
            for (int kk = 0; kk < 8; kk++) {
                wqA[kk] = *(const half8*)(wqbase + (g2*32 +      l15) * 256 + kk*32 + l4*8);
                wqB[kk] = *(const half8*)(wqbase + (g2*32 + 16 + l15) * 256 + kk*32 + l4*8);
            }
        }

        half8 ub = *(const half8*)&uadj[ntw*16 + l15][l4*8];
        #pragma unroll
        for (int dt = 0; dt < 8; dt++) accS[dt] = MFMA16(kfrag[dt], ub, accS[dt]);

        if (mh) {    // o = q@S + att@u_adj
            acc0 = MFMA16(att0, ub, acc0);
            acc1 = MFMA16(att1, ub, acc1);
            const size_t ob = ((size_t)bh * 4096 + (size_t)t * 32) * 256 + dv0 + ntw*16 + l15;
            #pragma unroll
            for (int j = 0; j < 4; j++) {
                outp[ob + (size_t)(l4*4 + j) * 256]      = acc0[j];
                outp[ob + (size_t)(16 + l4*4 + j) * 256] = acc1[j];
            }
        }
        // refresh fp16 S copy
        #pragma unroll
        for (int dt = 0; dt < 8; dt++) {
            u32x2 sw;
            sw.x = pk2(accS[dt][0], accS[dt][1]);
            sw.y = pk2(accS[dt][2], accS[dt][3]);
            *(u32x2*)&S_cm[ntw*16 + l15][mh*128 + dt*16 + l4*4] = sw;
        }
        __syncthreads();
    }

    // final state S -> d_out tail
    const size_t sb = (size_t)16777216 + ((size_t)bh * 256) * 256 + dv0 + ntw*16 + l15;
    #pragma unroll
    for (int dt = 0; dt < 8; dt++) {
        #pragma unroll
        for (int j = 0; j < 4; j++)
            outp[sb + (size_t)(mh*128 + dt*16 + l4*4 + j) * 256] = accS[dt][j];
    }
}

// ---------------------------------------------------------------- launch
extern "C" void kernel_launch(void* const* d_in, const int* in_sizes, int n_in,
                              void* d_out, int out_size, void* d_ws, size_t ws_size,
                              hipStream_t stream)
{
    (void)in_sizes; (void)n_in; (void)out_size; (void)ws_size;
    const float* q    = (const float*)d_in[0];
    const float* k    = (const float*)d_in[1];
    const float* v    = (const float*)d_in[2];
    const float* beta = (const float*)d_in[3];
    float* out = (float*)d_out;

    unsigned short* ws  = (unsigned short*)d_ws;
    const size_t SZ = (size_t)2048 * 32 * 256;        // 16.78M fp16 elems per tensor
    unsigned short* qn  = ws;
    unsigned short* ww  = ws + SZ;
    unsigned short* kT  = ws + 2 * SZ;
    unsigned short* uu  = ws + 3 * SZ;
    unsigned short* att = ws + 4 * SZ;                // 2048*1024 elems

    p1_kernel<<<2048, 256, 0, stream>>>(q, k, v, beta, qn, ww, kT, uu, att);
    p2_kernel<<<128, 256, 0, stream>>>(qn, ww, kT, uu, att, out);
}